// Round 1
// baseline (26985.226 us; speedup 1.0000x reference)
//
#include <hip/hip_runtime.h>
#include <cstdint>

#define T_STEPS 100
#define BATCH 256
#define NIN 700
#define H1 2048
#define H2 2048
#define NOUT 20

// ---------------- transpose 2048x2048 (W2->W2T, V->VT) ----------------
__global__ __launch_bounds__(256) void transpose2048_kernel(
    const float* __restrict__ W2, const float* __restrict__ V,
    float* __restrict__ W2T, float* __restrict__ VT)
{
    __shared__ float tile[32][33];
    const float* src = blockIdx.z ? V : W2;
    float* dst = blockIdx.z ? VT : W2T;
    const int tx = threadIdx.x, ty = threadIdx.y; // 32 x 8
    const int x = blockIdx.x * 32 + tx;
    const int y0 = blockIdx.y * 32;
    for (int r = ty; r < 32; r += 8)
        tile[r][tx] = src[(size_t)(y0 + r) * 2048 + x];
    __syncthreads();
    const int xo = blockIdx.y * 32 + tx;
    const int yo0 = blockIdx.x * 32;
    for (int r = ty; r < 32; r += 8)
        dst[(size_t)(yo0 + r) * 2048 + xo] = tile[tx][r];
}

// ---------------- layer 1: fused GEMM (x@W1.T) + leaky scan + bitpack ----
// grid (32 j-tiles, 256 b), block 256. Each block: all 100 t for one b,
// 64 j's. K=700 in tiles of 28. A staged [28][112] (t-padded), W [28][65].
__global__ __launch_bounds__(256) void l1_kernel(
    const float* __restrict__ data, const float* __restrict__ W1,
    const float* __restrict__ b1,
    const float* __restrict__ p_beta1, const float* __restrict__ p_thr1,
    unsigned long long* __restrict__ s1bits)
{
    __shared__ float lds[7168];          // union: A(3136)+W(1820) | C(7168)
    float* A  = lds;                     // [28][112], t in 0..111 (>=100 zero)
    float* Wl = lds + 3136;              // [28][65] (pad 65 -> conflict-free)
    const int jt = blockIdx.x, b = blockIdx.y;
    const int j0 = jt * 64;
    const int j = threadIdx.x & 63, g = threadIdx.x >> 6;
    float acc[28];
    #pragma unroll
    for (int i = 0; i < 28; ++i) acc[i] = 0.f;
    const float* db = data + (size_t)b * (NIN * T_STEPS);

    for (int k0 = 0; k0 < NIN; k0 += 28) {
        // stage A: 28 rows x (25 float4 data + 3 float4 zero pad)
        for (int idx = threadIdx.x; idx < 784; idx += 256) {
            int kk = idx / 28, q = idx - kk * 28;
            float4 v;
            if (q < 25) v = *(const float4*)(db + (size_t)(k0 + kk) * T_STEPS + q * 4);
            else { v.x = 0.f; v.y = 0.f; v.z = 0.f; v.w = 0.f; }
            *(float4*)(A + kk * 112 + q * 4) = v;
        }
        // stage W1 tile [28 k][64 j]
        for (int idx = threadIdx.x; idx < 1792; idx += 256) {
            int j2 = idx / 28, kk = idx - j2 * 28;
            Wl[kk * 65 + j2] = W1[(size_t)(j0 + j2) * NIN + k0 + kk];
        }
        __syncthreads();
        #pragma unroll 4
        for (int kk = 0; kk < 28; ++kk) {
            float wv = Wl[kk * 65 + j];
            const float4* av = (const float4*)(A + kk * 112 + g * 28);
            #pragma unroll
            for (int q = 0; q < 7; ++q) {
                float4 a4 = av[q];
                acc[q*4+0] = fmaf(a4.x, wv, acc[q*4+0]);
                acc[q*4+1] = fmaf(a4.y, wv, acc[q*4+1]);
                acc[q*4+2] = fmaf(a4.z, wv, acc[q*4+2]);
                acc[q*4+3] = fmaf(a4.w, wv, acc[q*4+3]);
            }
        }
        __syncthreads();
    }
    // dump C[t][j] to LDS, then wave 0 scans t sequentially per j-column
    #pragma unroll
    for (int tt = 0; tt < 28; ++tt)
        lds[(g * 28 + tt) * 64 + j] = acc[tt];
    __syncthreads();
    if (threadIdx.x < 64) {
        const float beta1 = *p_beta1, thr1 = *p_thr1;
        const float b1j = b1[j0 + j];
        float m = 0.f;
        for (int t = 0; t < T_STEPS; ++t) {
            m = fmaf(beta1, m, lds[t * 64 + j]) + b1j;
            bool pred = (m - thr1) > 0.f;
            unsigned long long mask = __ballot(pred);
            if (pred) m -= thr1;
            if (j == 0) s1bits[((size_t)t * BATCH + b) * 32 + jt] = mask;
        }
    }
}

// ---------------- layer 2 (per step): cur = s1@W2.T + spk_r@V.T + b2,
// AHP leaky neuron, write s_r bits (double-buffered). grid 256 = 8bt x 32jt,
// block 256 (j=lane, g=wave -> 8 b's each, acc[8]).
__global__ __launch_bounds__(256) void l2_kernel(
    const unsigned long long* __restrict__ s1bits_t,
    const unsigned long long* __restrict__ srb_in,
    unsigned long long* __restrict__ srb_out,
    const float* __restrict__ W2T, const float* __restrict__ VT,
    const float* __restrict__ b2,
    float* __restrict__ mem_r, float* __restrict__ ahp,
    const float* __restrict__ p_beta_r, const float* __restrict__ p_thr_r,
    const float* __restrict__ p_back_beta, const float* __restrict__ p_alpha)
{
    __shared__ float s_lds[256 * 32];    // [k-chunk 256][b 32]
    const int jt = blockIdx.x & 31, bt = blockIdx.x >> 5;
    const int j0 = jt * 64, b0 = bt * 32;
    const int j = threadIdx.x & 63, g = threadIdx.x >> 6;
    float acc[8];
    #pragma unroll
    for (int i = 0; i < 8; ++i) acc[i] = 0.f;
    const int bl = threadIdx.x & 31, wh = threadIdx.x >> 5;
    const int wword = wh >> 1, hlf = wh & 1;

    for (int half = 0; half < 2; ++half) {
        const unsigned long long* bits = half ? srb_in : s1bits_t;
        const float* WT = half ? VT : W2T;
        for (int kc = 0; kc < 8; ++kc) {
            // unpack 32b x 256k bits -> LDS floats [k][b]
            unsigned long long word = bits[(size_t)(b0 + bl) * 32 + kc * 4 + wword];
            unsigned int bw = (unsigned int)(word >> (hlf * 32));
            int kbase = wword * 64 + hlf * 32;
            #pragma unroll
            for (int i = 0; i < 32; ++i)
                s_lds[(kbase + i) * 32 + bl] = ((bw >> i) & 1u) ? 1.f : 0.f;
            __syncthreads();
            const float* wp = WT + ((size_t)kc * 256) * 2048 + j0 + j;
            #pragma unroll 8
            for (int k = 0; k < 256; ++k) {
                float wv = wp[(size_t)k * 2048];        // coalesced over lanes j
                const float4* sp = (const float4*)(s_lds + k * 32 + g * 8);
                float4 sa = sp[0], sb = sp[1];          // wave-uniform broadcast
                acc[0] = fmaf(sa.x, wv, acc[0]);
                acc[1] = fmaf(sa.y, wv, acc[1]);
                acc[2] = fmaf(sa.z, wv, acc[2]);
                acc[3] = fmaf(sa.w, wv, acc[3]);
                acc[4] = fmaf(sb.x, wv, acc[4]);
                acc[5] = fmaf(sb.y, wv, acc[5]);
                acc[6] = fmaf(sb.z, wv, acc[6]);
                acc[7] = fmaf(sb.w, wv, acc[7]);
            }
            __syncthreads();
        }
    }
    const float beta_r = *p_beta_r, thr_r = *p_thr_r;
    const float back_beta = *p_back_beta, alpha = *p_alpha;
    const float b2j = b2[j0 + j];
    #pragma unroll
    for (int u = 0; u < 8; ++u) {
        int b = b0 + g * 8 + u;
        size_t idx = (size_t)b * 2048 + j0 + j;
        float m = mem_r[idx], a = ahp[idx];
        float cur = acc[u] + b2j;
        m = fmaf(beta_r, m, cur) - a;
        bool pred = (m - thr_r) > 0.f;
        unsigned long long mask = __ballot(pred);
        float s = pred ? 1.f : 0.f;
        if (pred) m -= thr_r;
        a = fmaf(back_beta, a, alpha * s);
        mem_r[idx] = m;
        ahp[idx]  = a;
        if (j == 0) srb_out[(size_t)b * 32 + jt] = mask;
    }
}

// ---------------- layer 3 (per step): mem2 = beta2*mem2 + s_r@W3.T + b3 ----
// grid 256 (one wave per b); lane l covers k = 32l..32l+31.
__global__ __launch_bounds__(64) void l3_kernel(
    const unsigned int* __restrict__ srb32,
    const float* __restrict__ W3, const float* __restrict__ b3,
    float* __restrict__ mem2, float* __restrict__ out_t,
    const float* __restrict__ p_beta2, const float* __restrict__ p_thr2)
{
    const int b = blockIdx.x, l = threadIdx.x;
    unsigned int bits = srb32[b * 64 + l];
    float cur[NOUT];
    #pragma unroll
    for (int o = 0; o < NOUT; ++o) {
        const float* wp = W3 + (size_t)o * 2048 + l * 32;
        float s = 0.f;
        #pragma unroll
        for (int i = 0; i < 32; i += 4) {
            float4 w4 = *(const float4*)(wp + i);
            s += ((bits >> (i+0)) & 1u) ? w4.x : 0.f;
            s += ((bits >> (i+1)) & 1u) ? w4.y : 0.f;
            s += ((bits >> (i+2)) & 1u) ? w4.z : 0.f;
            s += ((bits >> (i+3)) & 1u) ? w4.w : 0.f;
        }
        #pragma unroll
        for (int msk = 32; msk > 0; msk >>= 1)
            s += __shfl_xor(s, msk, 64);
        cur[o] = s;
    }
    if (l == 0) {
        const float beta2 = *p_beta2, thr2 = *p_thr2;
        #pragma unroll
        for (int o = 0; o < NOUT; ++o) {
            float m = mem2[b * NOUT + o];
            m = fmaf(beta2, m, cur[o] + b3[o]);
            bool pred = (m - thr2) > 0.f;
            float s2 = pred ? 1.f : 0.f;
            if (pred) m -= thr2;
            mem2[b * NOUT + o] = m;
            out_t[b * NOUT + o] = s2;
        }
    }
}

extern "C" void kernel_launch(void* const* d_in, const int* in_sizes, int n_in,
                              void* d_out, int out_size, void* d_ws, size_t ws_size,
                              hipStream_t stream)
{
    const float* data   = (const float*)d_in[0];
    const float* W1     = (const float*)d_in[1];
    const float* b1     = (const float*)d_in[2];
    const float* W2     = (const float*)d_in[3];
    const float* b2     = (const float*)d_in[4];
    const float* V      = (const float*)d_in[5];
    const float* W3     = (const float*)d_in[6];
    const float* b3     = (const float*)d_in[7];
    const float* beta1  = (const float*)d_in[8];
    const float* thr1   = (const float*)d_in[9];
    const float* beta_r = (const float*)d_in[10];
    const float* thr_r  = (const float*)d_in[11];
    const float* back_beta = (const float*)d_in[12];
    const float* alpha  = (const float*)d_in[13];
    const float* beta2  = (const float*)d_in[14];
    const float* thr2   = (const float*)d_in[15];
    float* out = (float*)d_out;
    (void)in_sizes; (void)n_in; (void)out_size; (void)ws_size;

    char* p = (char*)d_ws;
    auto carve = [&](size_t bytes) {
        char* r = p; p += (bytes + 255) & ~(size_t)255; return r;
    };
    unsigned long long* s1bits = (unsigned long long*)carve((size_t)T_STEPS*BATCH*32*8); // 6.55 MB
    unsigned long long* srb0   = (unsigned long long*)carve((size_t)BATCH*32*8);
    unsigned long long* srb1   = (unsigned long long*)carve((size_t)BATCH*32*8);
    float* mem_r = (float*)carve((size_t)BATCH*H2*4);
    float* ahp   = (float*)carve((size_t)BATCH*H2*4);
    float* mem2  = (float*)carve((size_t)BATCH*NOUT*4);
    float* W2T   = (float*)carve((size_t)H2*H2*4);   // 16.8 MB
    float* VT    = (float*)carve((size_t)H2*H2*4);   // 16.8 MB

    hipMemsetAsync(srb0, 0, (size_t)BATCH*32*8, stream);
    hipMemsetAsync(mem_r, 0, (size_t)BATCH*H2*4, stream);
    hipMemsetAsync(ahp,  0, (size_t)BATCH*H2*4, stream);
    hipMemsetAsync(mem2, 0, (size_t)BATCH*NOUT*4, stream);

    transpose2048_kernel<<<dim3(64,64,2), dim3(32,8), 0, stream>>>(W2, V, W2T, VT);
    l1_kernel<<<dim3(32,256), 256, 0, stream>>>(data, W1, b1, beta1, thr1, s1bits);

    unsigned long long* srb[2] = {srb0, srb1};
    for (int t = 0; t < T_STEPS; ++t) {
        const unsigned long long* sin = srb[t & 1];
        unsigned long long* sout = srb[(t + 1) & 1];
        l2_kernel<<<256, 256, 0, stream>>>(s1bits + (size_t)t*BATCH*32, sin, sout,
                                           W2T, VT, b2, mem_r, ahp,
                                           beta_r, thr_r, back_beta, alpha);
        l3_kernel<<<256, 64, 0, stream>>>((const unsigned int*)sout, W3, b3, mem2,
                                          out + (size_t)t*BATCH*NOUT, beta2, thr2);
    }
}

// Round 2
// 7518.179 us; speedup vs baseline: 3.5893x; 3.5893x over previous
//
#include <hip/hip_runtime.h>
#include <hip/hip_bf16.h>
#include <cstdint>

#define T_STEPS 100
#define BATCH 256
#define NIN 700
#define H1 2048
#define H2 2048
#define NOUT 20
#define KS 8            // K-split factor for l2 GEMM
#define KCH 24          // 64-wide K chunks per block: 12288/(KS*64)

typedef __attribute__((ext_vector_type(8))) short bf16x8;
typedef __attribute__((ext_vector_type(4))) float f32x4;

__device__ __forceinline__ void async16(void* lds, const void* g) {
    __builtin_amdgcn_global_load_lds(
        (const __attribute__((address_space(1))) unsigned int*)g,
        (__attribute__((address_space(3))) unsigned int*)lds, 16, 0, 0);
}

__device__ __forceinline__ unsigned short f2bf(float x) {
    __hip_bfloat16 h = __float2bfloat16(x);
    return *(unsigned short*)&h;
}
__device__ __forceinline__ float bf2f(unsigned short u) {
    __hip_bfloat16 h = *(__hip_bfloat16*)&u;
    return __bfloat162float(h);
}

// ---------------- split W2|V into bf16 hi/mid/lo, layout [term][j][4096k] ----
// k<2048 -> W2[j][k]; k>=2048 -> V[j][k-2048]. 1.0*hi+1.0*mid+1.0*lo ~= w to 2^-25.
__global__ __launch_bounds__(256) void split_kernel(
    const float* __restrict__ W2, const float* __restrict__ V,
    unsigned short* __restrict__ Bsplit)
{
    const size_t D = (size_t)2048 * 4096;
    size_t i = (size_t)blockIdx.x * 256 + threadIdx.x;
    int j = (int)(i >> 12), k = (int)(i & 4095);
    float w = (k < 2048) ? W2[(size_t)j * 2048 + k] : V[(size_t)j * 2048 + (k - 2048)];
    unsigned short h = f2bf(w);
    float r1 = w - bf2f(h);
    unsigned short m = f2bf(r1);
    float r2 = r1 - bf2f(m);
    unsigned short l = f2bf(r2);
    Bsplit[i] = h;
    Bsplit[D + i] = m;
    Bsplit[2 * D + i] = l;
}

// ---------------- layer 1: fused GEMM (x@W1.T) + leaky scan + bitpack ----
__global__ __launch_bounds__(256) void l1_kernel(
    const float* __restrict__ data, const float* __restrict__ W1,
    const float* __restrict__ b1,
    const float* __restrict__ p_beta1, const float* __restrict__ p_thr1,
    unsigned long long* __restrict__ s1bits)
{
    __shared__ float lds[7168];
    float* A  = lds;                     // [28][112]
    float* Wl = lds + 3136;              // [28][65]
    const int jt = blockIdx.x, b = blockIdx.y;
    const int j0 = jt * 64;
    const int j = threadIdx.x & 63, g = threadIdx.x >> 6;
    float acc[28];
    #pragma unroll
    for (int i = 0; i < 28; ++i) acc[i] = 0.f;
    const float* db = data + (size_t)b * (NIN * T_STEPS);

    for (int k0 = 0; k0 < NIN; k0 += 28) {
        for (int idx = threadIdx.x; idx < 784; idx += 256) {
            int kk = idx / 28, q = idx - kk * 28;
            float4 v;
            if (q < 25) v = *(const float4*)(db + (size_t)(k0 + kk) * T_STEPS + q * 4);
            else { v.x = 0.f; v.y = 0.f; v.z = 0.f; v.w = 0.f; }
            *(float4*)(A + kk * 112 + q * 4) = v;
        }
        for (int idx = threadIdx.x; idx < 1792; idx += 256) {
            int j2 = idx / 28, kk = idx - j2 * 28;
            Wl[kk * 65 + j2] = W1[(size_t)(j0 + j2) * NIN + k0 + kk];
        }
        __syncthreads();
        #pragma unroll 4
        for (int kk = 0; kk < 28; ++kk) {
            float wv = Wl[kk * 65 + j];
            const float4* av = (const float4*)(A + kk * 112 + g * 28);
            #pragma unroll
            for (int q = 0; q < 7; ++q) {
                float4 a4 = av[q];
                acc[q*4+0] = fmaf(a4.x, wv, acc[q*4+0]);
                acc[q*4+1] = fmaf(a4.y, wv, acc[q*4+1]);
                acc[q*4+2] = fmaf(a4.z, wv, acc[q*4+2]);
                acc[q*4+3] = fmaf(a4.w, wv, acc[q*4+3]);
            }
        }
        __syncthreads();
    }
    #pragma unroll
    for (int tt = 0; tt < 28; ++tt)
        lds[(g * 28 + tt) * 64 + j] = acc[tt];
    __syncthreads();
    if (threadIdx.x < 64) {
        const float beta1 = *p_beta1, thr1 = *p_thr1;
        const float b1j = b1[j0 + j];
        float m = 0.f;
        for (int t = 0; t < T_STEPS; ++t) {
            m = fmaf(beta1, m, lds[t * 64 + j]) + b1j;
            bool pred = (m - thr1) > 0.f;
            unsigned long long mask = __ballot(pred);
            if (pred) m -= thr1;
            if (j == 0) s1bits[((size_t)t * BATCH + b) * 32 + jt] = mask;
        }
    }
}

// ---------------- l2 GEMM (per step): Cpart[ks][256b][2048j] partials --------
// flat K = 3 terms x 4096 (k<2048: s1, else srb). BM=128 BN=64, 2 waves,
// each wave 64x64 via 4x4 of 16x16x32 bf16 MFMA. XOR-swizzled LDS granules.
__global__ __launch_bounds__(128) void l2gemm_kernel(
    const unsigned long long* __restrict__ s1bits_t,
    const unsigned long long* __restrict__ srb_in,
    const unsigned short* __restrict__ Bsplit,
    float* __restrict__ Cpart)
{
    __shared__ unsigned short Alds[128 * 64];   // 128 rows x 8 granules(8 bf16) 16KB
    __shared__ unsigned short Blds[64 * 64];    // 64 rows x 8 granules         8KB
    const int bid = blockIdx.x;
    const int nt = bid & 31, mt = (bid >> 5) & 1, ks = bid >> 6;
    const int m0 = mt << 7, n0 = nt << 6;
    const int t = threadIdx.x;
    const int lane = t & 63, w = t >> 6;
    f32x4 acc[4][4] = {};

    const int fbase = ks * 1536;
    for (int c = 0; c < KCH; ++c) {
        const int f = fbase + (c << 6);
        const int term = f >> 12;
        const int kin = f & 4095;
        // B tile: rows n0..n0+63, k kin..kin+63 (async, lane-permuted for swizzle)
        const unsigned short* Bg = Bsplit + ((size_t)term << 23);
        #pragma unroll
        for (int i = 0; i < 4; ++i) {
            int rl = (w << 5) + (i << 3) + (lane >> 3);       // local row 0..63
            int k16s = (lane & 7) ^ (rl & 7);                 // source granule
            const unsigned short* g = Bg + (size_t)(n0 + rl) * 4096 + kin + (k16s << 3);
            async16(Blds + (((w << 5) + (i << 3)) << 6), (const void*)g);
        }
        // A tile: unpack one 64-bit spike word per row (thread t -> row t)
        {
            int b = m0 + t;
            unsigned long long word = (kin < 2048)
                ? s1bits_t[((size_t)b << 5) + (kin >> 6)]
                : srb_in[((size_t)b << 5) + ((kin - 2048) >> 6)];
            #pragma unroll
            for (int g8 = 0; g8 < 8; ++g8) {
                unsigned int u[4];
                #pragma unroll
                for (int p = 0; p < 4; ++p) {
                    int bit = (g8 << 3) + (p << 1);
                    u[p] = (((word >> bit) & 1ull) ? 0x3F80u : 0u)
                         | (((word >> (bit + 1)) & 1ull) ? 0x3F800000u : 0u);
                }
                int gdst = (t << 3) + (g8 ^ (t & 7));
                *(uint4*)(Alds + (gdst << 3)) = *(uint4*)u;
            }
        }
        __syncthreads();   // drains vmcnt (global_load_lds) + lds writes
        #pragma unroll
        for (int kk = 0; kk < 2; ++kk) {
            bf16x8 af[4], bfr[4];
            const int q = lane >> 4, k16 = (kk << 2) + q;
            #pragma unroll
            for (int i = 0; i < 4; ++i) {
                int ra = (w << 6) + (i << 4) + (lane & 15);
                af[i] = *(const bf16x8*)(Alds + (((ra << 3) + (k16 ^ (ra & 7))) << 3));
            }
            #pragma unroll
            for (int j = 0; j < 4; ++j) {
                int rb = (j << 4) + (lane & 15);
                bfr[j] = *(const bf16x8*)(Blds + (((rb << 3) + (k16 ^ (rb & 7))) << 3));
            }
            #pragma unroll
            for (int i = 0; i < 4; ++i)
                #pragma unroll
                for (int j = 0; j < 4; ++j)
                    acc[i][j] = __builtin_amdgcn_mfma_f32_16x16x32_bf16(af[i], bfr[j], acc[i][j], 0, 0, 0);
        }
        __syncthreads();
    }
    float* Cp = Cpart + ((size_t)ks << 19);
    #pragma unroll
    for (int i = 0; i < 4; ++i) {
        int rg = m0 + (w << 6) + (i << 4) + ((lane >> 4) << 2);
        #pragma unroll
        for (int j = 0; j < 4; ++j) {
            int cg = n0 + (j << 4) + (lane & 15);
            #pragma unroll
            for (int r = 0; r < 4; ++r)
                Cp[(size_t)(rg + r) * 2048 + cg] = acc[i][j][r];
        }
    }
}

// ---------------- finish (per step): sum partials, AHP neuron, bits, layer3 --
__global__ __launch_bounds__(256) void l2fin_kernel(
    const float* __restrict__ Cpart, const float* __restrict__ b2,
    float* __restrict__ mem_r, float* __restrict__ ahp,
    unsigned long long* __restrict__ srb_out,
    const float* __restrict__ W3, const float* __restrict__ b3,
    float* __restrict__ mem2, float* __restrict__ out_t,
    const float* __restrict__ p_beta_r, const float* __restrict__ p_thr_r,
    const float* __restrict__ p_back_beta, const float* __restrict__ p_alpha,
    const float* __restrict__ p_beta2, const float* __restrict__ p_thr2)
{
    __shared__ float sLDS[2048];
    __shared__ float red[4][NOUT];
    const int b = blockIdx.x, t = threadIdx.x;
    const int lane = t & 63, wv = t >> 6;
    const float beta_r = *p_beta_r, thr_r = *p_thr_r;
    const float bb = *p_back_beta, al = *p_alpha;
    #pragma unroll
    for (int u = 0; u < 8; ++u) {
        int j = t + (u << 8);
        size_t cidx = (size_t)b * 2048 + j;
        float x = 0.f;
        #pragma unroll
        for (int p = 0; p < KS; ++p) x += Cpart[((size_t)p << 19) + cidx];
        float cur = x + b2[j];
        float m = fmaf(beta_r, mem_r[cidx], cur) - ahp[cidx];
        bool pred = (m - thr_r) > 0.f;
        unsigned long long mask = __ballot(pred);
        float s = pred ? 1.f : 0.f;
        if (pred) m -= thr_r;
        mem_r[cidx] = m;
        ahp[cidx] = fmaf(bb, ahp[cidx], al * s);
        sLDS[j] = s;
        if (lane == 0) srb_out[((size_t)b << 5) + (u << 2) + wv] = mask;
    }
    __syncthreads();
    // layer 3: thread t covers k = t*8..t*8+7
    float s8[8];
    #pragma unroll
    for (int i = 0; i < 8; ++i) s8[i] = sLDS[t * 8 + i];
    float po[NOUT];
    #pragma unroll
    for (int o = 0; o < NOUT; ++o) {
        const float4* wp = (const float4*)(W3 + (size_t)o * 2048 + t * 8);
        float4 wa = wp[0], wb2 = wp[1];
        float v = s8[0]*wa.x + s8[1]*wa.y + s8[2]*wa.z + s8[3]*wa.w
                + s8[4]*wb2.x + s8[5]*wb2.y + s8[6]*wb2.z + s8[7]*wb2.w;
        #pragma unroll
        for (int msk = 32; msk > 0; msk >>= 1)
            v += __shfl_xor(v, msk, 64);
        po[o] = v;
    }
    if (lane == 0) {
        #pragma unroll
        for (int o = 0; o < NOUT; ++o) red[wv][o] = po[o];
    }
    __syncthreads();
    if (t < NOUT) {
        const float beta2 = *p_beta2, thr2 = *p_thr2;
        float cur = red[0][t] + red[1][t] + red[2][t] + red[3][t] + b3[t];
        float m = fmaf(beta2, mem2[b * NOUT + t], cur);
        bool pred = (m - thr2) > 0.f;
        float s2 = pred ? 1.f : 0.f;
        if (pred) m -= thr2;
        mem2[b * NOUT + t] = m;
        out_t[b * NOUT + t] = s2;
    }
}

extern "C" void kernel_launch(void* const* d_in, const int* in_sizes, int n_in,
                              void* d_out, int out_size, void* d_ws, size_t ws_size,
                              hipStream_t stream)
{
    const float* data   = (const float*)d_in[0];
    const float* W1     = (const float*)d_in[1];
    const float* b1     = (const float*)d_in[2];
    const float* W2     = (const float*)d_in[3];
    const float* b2     = (const float*)d_in[4];
    const float* V      = (const float*)d_in[5];
    const float* W3     = (const float*)d_in[6];
    const float* b3     = (const float*)d_in[7];
    const float* beta1  = (const float*)d_in[8];
    const float* thr1   = (const float*)d_in[9];
    const float* beta_r = (const float*)d_in[10];
    const float* thr_r  = (const float*)d_in[11];
    const float* back_beta = (const float*)d_in[12];
    const float* alpha  = (const float*)d_in[13];
    const float* beta2  = (const float*)d_in[14];
    const float* thr2   = (const float*)d_in[15];
    float* out = (float*)d_out;
    (void)in_sizes; (void)n_in; (void)out_size; (void)ws_size;

    char* p = (char*)d_ws;
    auto carve = [&](size_t bytes) {
        char* r = p; p += (bytes + 255) & ~(size_t)255; return r;
    };
    unsigned long long* s1bits = (unsigned long long*)carve((size_t)T_STEPS*BATCH*32*8);
    unsigned long long* srb0   = (unsigned long long*)carve((size_t)BATCH*32*8);
    unsigned long long* srb1   = (unsigned long long*)carve((size_t)BATCH*32*8);
    float* mem_r = (float*)carve((size_t)BATCH*H2*4);
    float* ahp   = (float*)carve((size_t)BATCH*H2*4);
    float* mem2  = (float*)carve((size_t)BATCH*NOUT*4);
    unsigned short* Bsplit = (unsigned short*)carve((size_t)3*2048*4096*2);  // 50.3 MB
    float* Cpart = (float*)carve((size_t)KS*BATCH*H2*4);                     // 16.8 MB

    hipMemsetAsync(srb0, 0, (size_t)BATCH*32*8, stream);
    hipMemsetAsync(mem_r, 0, (size_t)BATCH*H2*4, stream);
    hipMemsetAsync(ahp,  0, (size_t)BATCH*H2*4, stream);
    hipMemsetAsync(mem2, 0, (size_t)BATCH*NOUT*4, stream);

    split_kernel<<<(2048*4096)/256, 256, 0, stream>>>(W2, V, Bsplit);
    l1_kernel<<<dim3(32,256), 256, 0, stream>>>(data, W1, b1, beta1, thr1, s1bits);

    unsigned long long* srb[2] = {srb0, srb1};
    for (int t = 0; t < T_STEPS; ++t) {
        const unsigned long long* sin = srb[t & 1];
        unsigned long long* sout = srb[(t + 1) & 1];
        l2gemm_kernel<<<512, 128, 0, stream>>>(s1bits + (size_t)t*BATCH*32, sin,
                                               Bsplit, Cpart);
        l2fin_kernel<<<256, 256, 0, stream>>>(Cpart, b2, mem_r, ahp, sout,
                                              W3, b3, mem2, out + (size_t)t*BATCH*NOUT,
                                              beta_r, thr_r, back_beta, alpha,
                                              beta2, thr2);
    }
}

// Round 3
// 6262.412 us; speedup vs baseline: 4.3091x; 1.2005x over previous
//
#include <hip/hip_runtime.h>
#include <hip/hip_bf16.h>
#include <cstdint>

#define T_STEPS 100
#define BATCH 256
#define NIN 700
#define H1 2048
#define H2 2048
#define NOUT 20
#define KS 16           // K-split factor for l2 GEMM
#define KCH 12          // 64-wide K chunks per block: 12288/(KS*64)

typedef __attribute__((ext_vector_type(8))) short bf16x8;
typedef __attribute__((ext_vector_type(4))) float f32x4;

__device__ __forceinline__ void async16(void* lds, const void* g) {
    __builtin_amdgcn_global_load_lds(
        (const __attribute__((address_space(1))) unsigned int*)g,
        (__attribute__((address_space(3))) unsigned int*)lds, 16, 0, 0);
}

__device__ __forceinline__ unsigned short f2bf(float x) {
    __hip_bfloat16 h = __float2bfloat16(x);
    return *(unsigned short*)&h;
}
__device__ __forceinline__ float bf2f(unsigned short u) {
    __hip_bfloat16 h = *(__hip_bfloat16*)&u;
    return __bfloat162float(h);
}

// ---------------- split W2|V into bf16 hi/mid/lo, layout [term][j][4096k] ----
__global__ __launch_bounds__(256) void split_kernel(
    const float* __restrict__ W2, const float* __restrict__ V,
    unsigned short* __restrict__ Bsplit)
{
    const size_t D = (size_t)2048 * 4096;
    size_t i = (size_t)blockIdx.x * 256 + threadIdx.x;
    int j = (int)(i >> 12), k = (int)(i & 4095);
    float w = (k < 2048) ? W2[(size_t)j * 2048 + k] : V[(size_t)j * 2048 + (k - 2048)];
    unsigned short h = f2bf(w);
    float r1 = w - bf2f(h);
    unsigned short m = f2bf(r1);
    float r2 = r1 - bf2f(m);
    unsigned short l = f2bf(r2);
    Bsplit[i] = h;
    Bsplit[D + i] = m;
    Bsplit[2 * D + i] = l;
}

// ---------------- layer 1: fused GEMM (x@W1.T) + leaky scan + bitpack ----
__global__ __launch_bounds__(256) void l1_kernel(
    const float* __restrict__ data, const float* __restrict__ W1,
    const float* __restrict__ b1,
    const float* __restrict__ p_beta1, const float* __restrict__ p_thr1,
    unsigned long long* __restrict__ s1bits)
{
    __shared__ float lds[7168];
    float* A  = lds;                     // [28][112]
    float* Wl = lds + 3136;              // [28][65]
    const int jt = blockIdx.x, b = blockIdx.y;
    const int j0 = jt * 64;
    const int j = threadIdx.x & 63, g = threadIdx.x >> 6;
    float acc[28];
    #pragma unroll
    for (int i = 0; i < 28; ++i) acc[i] = 0.f;
    const float* db = data + (size_t)b * (NIN * T_STEPS);

    for (int k0 = 0; k0 < NIN; k0 += 28) {
        for (int idx = threadIdx.x; idx < 784; idx += 256) {
            int kk = idx / 28, q = idx - kk * 28;
            float4 v;
            if (q < 25) v = *(const float4*)(db + (size_t)(k0 + kk) * T_STEPS + q * 4);
            else { v.x = 0.f; v.y = 0.f; v.z = 0.f; v.w = 0.f; }
            *(float4*)(A + kk * 112 + q * 4) = v;
        }
        for (int idx = threadIdx.x; idx < 1792; idx += 256) {
            int j2 = idx / 28, kk = idx - j2 * 28;
            Wl[kk * 65 + j2] = W1[(size_t)(j0 + j2) * NIN + k0 + kk];
        }
        __syncthreads();
        #pragma unroll 4
        for (int kk = 0; kk < 28; ++kk) {
            float wv = Wl[kk * 65 + j];
            const float4* av = (const float4*)(A + kk * 112 + g * 28);
            #pragma unroll
            for (int q = 0; q < 7; ++q) {
                float4 a4 = av[q];
                acc[q*4+0] = fmaf(a4.x, wv, acc[q*4+0]);
                acc[q*4+1] = fmaf(a4.y, wv, acc[q*4+1]);
                acc[q*4+2] = fmaf(a4.z, wv, acc[q*4+2]);
                acc[q*4+3] = fmaf(a4.w, wv, acc[q*4+3]);
            }
        }
        __syncthreads();
    }
    #pragma unroll
    for (int tt = 0; tt < 28; ++tt)
        lds[(g * 28 + tt) * 64 + j] = acc[tt];
    __syncthreads();
    if (threadIdx.x < 64) {
        const float beta1 = *p_beta1, thr1 = *p_thr1;
        const float b1j = b1[j0 + j];
        float m = 0.f;
        for (int t = 0; t < T_STEPS; ++t) {
            m = fmaf(beta1, m, lds[t * 64 + j]) + b1j;
            bool pred = (m - thr1) > 0.f;
            unsigned long long mask = __ballot(pred);
            if (pred) m -= thr1;
            if (j == 0) s1bits[((size_t)t * BATCH + b) * 32 + jt] = mask;
        }
    }
}

// ---------------- l2 GEMM (per step): Cpart[ks][256b][2048j] partials --------
// BM=256 (all b), BN=64, KS=16. Block 256 thr / 4 waves, wave-tile 64x64.
// grid 512 = 32 nt x 16 ks -> 2 blocks/CU, 8 waves/CU.
__global__ __launch_bounds__(256, 2) void l2gemm_kernel(
    const unsigned long long* __restrict__ s1bits_t,
    const unsigned long long* __restrict__ srb_in,
    const unsigned short* __restrict__ Bsplit,
    float* __restrict__ Cpart)
{
    __shared__ __align__(16) unsigned short Alds[256 * 64];  // 256 rows x 8 gran 32KB
    __shared__ __align__(16) unsigned short Blds[64 * 64];   // 64 rows x 8 gran   8KB
    const int bid = blockIdx.x;
    const int nt = bid & 31, ks = bid >> 5;
    const int n0 = nt << 6;
    const int t = threadIdx.x;
    const int lane = t & 63, w = t >> 6;
    f32x4 acc[4][4] = {};

    const int fbase = ks * (12288 / KS);
    for (int c = 0; c < KCH; ++c) {
        const int f = fbase + (c << 6);
        const int term = f >> 12;
        const int kin = f & 4095;
        // B tile: rows n0..n0+63, k kin..kin+63 (async, lane-permuted swizzle)
        const unsigned short* Bg = Bsplit + ((size_t)term << 23);
        #pragma unroll
        for (int i = 0; i < 2; ++i) {
            int d = (w << 7) + (i << 6) + lane;           // dst granule (lane-linear)
            int row = d >> 3, g8 = d & 7;
            int k16s = g8 ^ (row & 7);
            const unsigned short* g = Bg + (size_t)(n0 + row) * 4096 + kin + (k16s << 3);
            async16(Blds + (((w << 7) + (i << 6)) << 3), (const void*)g);
        }
        // A tile: thread t -> batch row t, unpack 64 spike bits -> 8 granules
        {
            unsigned long long word = (kin < 2048)
                ? s1bits_t[((size_t)t << 5) + (kin >> 6)]
                : srb_in[((size_t)t << 5) + ((kin - 2048) >> 6)];
            #pragma unroll
            for (int g8 = 0; g8 < 8; ++g8) {
                unsigned int u[4];
                #pragma unroll
                for (int p = 0; p < 4; ++p) {
                    int bit = (g8 << 3) + (p << 1);
                    u[p] = (((word >> bit) & 1ull) ? 0x3F80u : 0u)
                         | (((word >> (bit + 1)) & 1ull) ? 0x3F800000u : 0u);
                }
                int gdst = (t << 3) + (g8 ^ (t & 7));
                *(uint4*)(Alds + (gdst << 3)) = *(uint4*)u;
            }
        }
        __syncthreads();
        #pragma unroll
        for (int kk = 0; kk < 2; ++kk) {
            bf16x8 af[4], bfr[4];
            const int q = lane >> 4, k16 = (kk << 2) + q;
            #pragma unroll
            for (int i = 0; i < 4; ++i) {
                int ra = (w << 6) + (i << 4) + (lane & 15);
                af[i] = *(const bf16x8*)(Alds + (((ra << 3) + (k16 ^ (ra & 7))) << 3));
            }
            #pragma unroll
            for (int j = 0; j < 4; ++j) {
                int rb = (j << 4) + (lane & 15);
                bfr[j] = *(const bf16x8*)(Blds + (((rb << 3) + (k16 ^ (rb & 7))) << 3));
            }
            #pragma unroll
            for (int i = 0; i < 4; ++i)
                #pragma unroll
                for (int j = 0; j < 4; ++j)
                    acc[i][j] = __builtin_amdgcn_mfma_f32_16x16x32_bf16(af[i], bfr[j], acc[i][j], 0, 0, 0);
        }
        __syncthreads();
    }
    float* Cp = Cpart + ((size_t)ks << 19);
    #pragma unroll
    for (int i = 0; i < 4; ++i) {
        int rg = (w << 6) + (i << 4) + ((lane >> 4) << 2);
        #pragma unroll
        for (int j = 0; j < 4; ++j) {
            int cg = n0 + (j << 4) + (lane & 15);
            #pragma unroll
            for (int r = 0; r < 4; ++r)
                Cp[(size_t)(rg + r) * 2048 + cg] = acc[i][j][r];
        }
    }
}

// ---------------- finish (per step): sum partials, AHP neuron, bits, layer3 --
__global__ __launch_bounds__(256) void l2fin_kernel(
    const float* __restrict__ Cpart, const float* __restrict__ b2,
    float* __restrict__ mem_r, float* __restrict__ ahp,
    unsigned long long* __restrict__ srb_out,
    const float* __restrict__ W3, const float* __restrict__ b3,
    float* __restrict__ mem2, float* __restrict__ out_t,
    const float* __restrict__ p_beta_r, const float* __restrict__ p_thr_r,
    const float* __restrict__ p_back_beta, const float* __restrict__ p_alpha,
    const float* __restrict__ p_beta2, const float* __restrict__ p_thr2)
{
    __shared__ float sLDS[2048];
    __shared__ float red[4][NOUT];
    const int b = blockIdx.x, t = threadIdx.x;
    const int lane = t & 63, wv = t >> 6;
    const float beta_r = *p_beta_r, thr_r = *p_thr_r;
    const float bb = *p_back_beta, al = *p_alpha;
    #pragma unroll
    for (int u = 0; u < 8; ++u) {
        int j = t + (u << 8);
        size_t cidx = (size_t)b * 2048 + j;
        float x = 0.f;
        #pragma unroll
        for (int p = 0; p < KS; ++p) x += Cpart[((size_t)p << 19) + cidx];
        float cur = x + b2[j];
        float m = fmaf(beta_r, mem_r[cidx], cur) - ahp[cidx];
        bool pred = (m - thr_r) > 0.f;
        unsigned long long mask = __ballot(pred);
        float s = pred ? 1.f : 0.f;
        if (pred) m -= thr_r;
        mem_r[cidx] = m;
        ahp[cidx] = fmaf(bb, ahp[cidx], al * s);
        sLDS[j] = s;
        if (lane == 0) srb_out[((size_t)b << 5) + (u << 2) + wv] = mask;
    }
    __syncthreads();
    float s8[8];
    #pragma unroll
    for (int i = 0; i < 8; ++i) s8[i] = sLDS[t * 8 + i];
    float po[NOUT];
    #pragma unroll
    for (int o = 0; o < NOUT; ++o) {
        const float4* wp = (const float4*)(W3 + (size_t)o * 2048 + t * 8);
        float4 wa = wp[0], wb2 = wp[1];
        float v = s8[0]*wa.x + s8[1]*wa.y + s8[2]*wa.z + s8[3]*wa.w
                + s8[4]*wb2.x + s8[5]*wb2.y + s8[6]*wb2.z + s8[7]*wb2.w;
        #pragma unroll
        for (int msk = 32; msk > 0; msk >>= 1)
            v += __shfl_xor(v, msk, 64);
        po[o] = v;
    }
    if (lane == 0) {
        #pragma unroll
        for (int o = 0; o < NOUT; ++o) red[wv][o] = po[o];
    }
    __syncthreads();
    if (t < NOUT) {
        const float beta2 = *p_beta2, thr2 = *p_thr2;
        float cur = red[0][t] + red[1][t] + red[2][t] + red[3][t] + b3[t];
        float m = fmaf(beta2, mem2[b * NOUT + t], cur);
        bool pred = (m - thr2) > 0.f;
        float s2 = pred ? 1.f : 0.f;
        if (pred) m -= thr2;
        mem2[b * NOUT + t] = m;
        out_t[b * NOUT + t] = s2;
    }
}

extern "C" void kernel_launch(void* const* d_in, const int* in_sizes, int n_in,
                              void* d_out, int out_size, void* d_ws, size_t ws_size,
                              hipStream_t stream)
{
    const float* data   = (const float*)d_in[0];
    const float* W1     = (const float*)d_in[1];
    const float* b1     = (const float*)d_in[2];
    const float* W2     = (const float*)d_in[3];
    const float* b2     = (const float*)d_in[4];
    const float* V      = (const float*)d_in[5];
    const float* W3     = (const float*)d_in[6];
    const float* b3     = (const float*)d_in[7];
    const float* beta1  = (const float*)d_in[8];
    const float* thr1   = (const float*)d_in[9];
    const float* beta_r = (const float*)d_in[10];
    const float* thr_r  = (const float*)d_in[11];
    const float* back_beta = (const float*)d_in[12];
    const float* alpha  = (const float*)d_in[13];
    const float* beta2  = (const float*)d_in[14];
    const float* thr2   = (const float*)d_in[15];
    float* out = (float*)d_out;
    (void)in_sizes; (void)n_in; (void)out_size; (void)ws_size;

    char* p = (char*)d_ws;
    auto carve = [&](size_t bytes) {
        char* r = p; p += (bytes + 255) & ~(size_t)255; return r;
    };
    unsigned long long* s1bits = (unsigned long long*)carve((size_t)T_STEPS*BATCH*32*8);
    unsigned long long* srb0   = (unsigned long long*)carve((size_t)BATCH*32*8);
    unsigned long long* srb1   = (unsigned long long*)carve((size_t)BATCH*32*8);
    float* mem_r = (float*)carve((size_t)BATCH*H2*4);
    float* ahp   = (float*)carve((size_t)BATCH*H2*4);
    float* mem2  = (float*)carve((size_t)BATCH*NOUT*4);
    unsigned short* Bsplit = (unsigned short*)carve((size_t)3*2048*4096*2);  // 50.3 MB
    float* Cpart = (float*)carve((size_t)KS*BATCH*H2*4);                     // 33.6 MB

    hipMemsetAsync(srb0, 0, (size_t)BATCH*32*8, stream);
    hipMemsetAsync(mem_r, 0, (size_t)BATCH*H2*4, stream);
    hipMemsetAsync(ahp,  0, (size_t)BATCH*H2*4, stream);
    hipMemsetAsync(mem2, 0, (size_t)BATCH*NOUT*4, stream);

    split_kernel<<<(2048*4096)/256, 256, 0, stream>>>(W2, V, Bsplit);
    l1_kernel<<<dim3(32,256), 256, 0, stream>>>(data, W1, b1, beta1, thr1, s1bits);

    unsigned long long* srb[2] = {srb0, srb1};
    for (int t = 0; t < T_STEPS; ++t) {
        const unsigned long long* sin = srb[t & 1];
        unsigned long long* sout = srb[(t + 1) & 1];
        l2gemm_kernel<<<512, 256, 0, stream>>>(s1bits + (size_t)t*BATCH*32, sin,
                                               Bsplit, Cpart);
        l2fin_kernel<<<256, 256, 0, stream>>>(Cpart, b2, mem_r, ahp, sout,
                                              W3, b3, mem2, out + (size_t)t*BATCH*NOUT,
                                              beta_r, thr_r, back_beta, alpha,
                                              beta2, thr2);
    }
}